// Round 11
// baseline (90.048 us; speedup 1.0000x reference)
//
#include <hip/hip_runtime.h>
#include <math.h>
#include <stdint.h>

#define N_NODES 8192
#define D 7
#define K 32
#define NT 512
#define QB 8
#define CPT (N_NODES / NT)
#define SCAP 320             // screen-survivor capacity per query
#define ECAP2 256            // exact-pruned rank capacity per query
#define DELTA 0.125f         // f16 screen error bound (analytic <= ~0.09)

typedef unsigned long long u64;
typedef _Float16 h2 __attribute__((ext_vector_type(2)));
typedef _Float16 f16x8 __attribute__((ext_vector_type(8)));
typedef float f32x4 __attribute__((ext_vector_type(4)));
union U4H8 { uint4 u; f16x8 h; };

__device__ __forceinline__ float rfl(float v) {
    return __uint_as_float(__builtin_amdgcn_readfirstlane(__float_as_uint(v)));
}
__device__ __forceinline__ unsigned pkh(float a, float b) {
    union { h2 h; unsigned u; } t;
    t.h[0] = (_Float16)a; t.h[1] = (_Float16)b; return t.u;
}
// order-preserving float<->uint (total order)
__device__ __forceinline__ unsigned ordu(float f) {
    unsigned u = __float_as_uint(f);
    return (u & 0x80000000u) ? ~u : (u | 0x80000000u);
}
__device__ __forceinline__ float unordu(unsigned o) {
    unsigned u = (o & 0x80000000u) ? (o & 0x7fffffffu) : ~o;
    return __uint_as_float(u);
}

// exact m = sqj - 2*dot(fi, fj); identical rounding chain everywhere.
__device__ __forceinline__ float dist_m(float4 b0, float4 b1, float sqj,
                                        float4 A, float4 B) {
    float dot = A.x * b0.x;
    dot = fmaf(A.y, b0.y, dot);
    dot = fmaf(A.z, b0.z, dot);
    dot = fmaf(A.w, b0.w, dot);
    dot = fmaf(B.x, b1.x, dot);
    dot = fmaf(B.y, b1.y, dot);
    dot = fmaf(B.z, b1.z, dot);
    return fmaf(-2.0f, dot, sqj);
}

// ---------------------------------------------------------------------------
// Kernel 1: outb = clip(feat @ W^T), fh = f16 [f0..f6,sq] (16 B/node),
//           xsq = f32 [f0..f6, sq] (32 B/node).
// ---------------------------------------------------------------------------
__global__ __launch_bounds__(256)
void precompute_kernel(const float* __restrict__ x, const float* __restrict__ W,
                       float* __restrict__ outb, uint4* __restrict__ fh,
                       float4* __restrict__ xsq4)
{
    int n = blockIdx.x * 256 + threadIdx.x;
    float4 v0 = *reinterpret_cast<const float4*>(x + n * 8);
    float4 v1 = *reinterpret_cast<const float4*>(x + n * 8 + 4);
    float f[D] = {v0.x, v0.y, v0.z, v0.w, v1.x, v1.y, v1.z};
    float sq = 0.f;
#pragma unroll
    for (int c = 0; c < D; ++c) sq += f[c] * f[c];
    uint4 h;
    h.x = pkh(f[0], f[1]); h.y = pkh(f[2], f[3]);
    h.z = pkh(f[4], f[5]); h.w = pkh(f[6], sq);
    fh[n] = h;
    xsq4[n * 2]     = v0;
    xsq4[n * 2 + 1] = make_float4(v1.x, v1.y, v1.z, sq);
#pragma unroll
    for (int r = 0; r < D; ++r) {
        float acc = 0.f;
#pragma unroll
        for (int c = 0; c < D; ++c) acc += f[c] * W[r * D + c];
        acc = fminf(fmaxf(acc, -1.f), 1.f);
        outb[n * D + r] = acc;
    }
}

// ---------------------------------------------------------------------------
// Kernel 2: exact top-32 (jax.lax.top_k order) + attention.
// MFMA f16 screen (A=node rows from fh, B=[-2f_q,1]) -> 34th-of-128
// slot-min ballot-bisect threshold -> MFMA survivor extraction ->
// exact fp32 prune -> rank-by-count. Cold exact fallback retained.
// ---------------------------------------------------------------------------
__global__ __launch_bounds__(NT, 4)
void gat_kernel(const float* __restrict__ x, const float* __restrict__ aw,
                const float* __restrict__ outb, const uint4* __restrict__ fh,
                const float4* __restrict__ xs4, float* __restrict__ dout)
{
    __shared__ u64      cand[QB][ECAP2];      // 16 KB (aliases Lmin[128][16])
    __shared__ unsigned short ent[QB][SCAP];  // 5 KB
    __shared__ int      nbr[QB][K];
    __shared__ uint4    qpk[16];              // B-operand rows (8 real + 8 zero)
    __shared__ float    sqfL[QB];
    __shared__ unsigned selT[QB];
    __shared__ float    exqL[QB];             // exact prune threshold
    __shared__ float    scrL[16];             // screen threshold per col
    __shared__ int      scnt[QB];
    __shared__ int      cnt2[QB];
    __shared__ float    redv[8];
    __shared__ int      redi[8];
    __shared__ float    bcv;
    __shared__ int      bci;

    float* Lmin = (float*)cand;               // [128 slots][16 cols] f32, 8 KB

    const int tid  = threadIdx.x;
    const int lane = tid & 63;
    const int wave = tid >> 6;
    const int i0   = blockIdx.x * QB;
    const int col  = lane & 15;
    const int lg   = lane >> 4;

    // exact f32 query scalars -> SGPR (static indexing only)
    float4 qA[QB], qBv[QB];
    float sqi[QB];
#pragma unroll
    for (int q = 0; q < QB; ++q) {
        const float* xq = x + (i0 + q) * 8;
        float4 a0 = *reinterpret_cast<const float4*>(xq);
        float4 a1 = *reinterpret_cast<const float4*>(xq + 4);
        float sq_ = rfl(xs4[(i0 + q) * 2 + 1].w);
        qA[q].x  = rfl(a0.x); qA[q].y  = rfl(a0.y);
        qA[q].z  = rfl(a0.z); qA[q].w  = rfl(a0.w);
        qBv[q].x = rfl(a1.x); qBv[q].y = rfl(a1.y);
        qBv[q].z = rfl(a1.z); qBv[q].w = sq_;
        sqi[q]   = sq_;
    }
    if (tid < 16) {
        if (tid < QB) {
            const float* xq = x + (i0 + tid) * 8;
            float f0 = xq[0], f1 = xq[1], f2 = xq[2], f3 = xq[3];
            float f4 = xq[4], f5 = xq[5], f6 = xq[6];
            qpk[tid] = make_uint4(pkh(-2.f * f0, -2.f * f1),
                                  pkh(-2.f * f2, -2.f * f3),
                                  pkh(-2.f * f4, -2.f * f5),
                                  pkh(-2.f * f6, 1.0f));
            sqfL[tid] = f0*f0 + f1*f1 + f2*f2 + f3*f3 + f4*f4 + f5*f5 + f6*f6;
            scnt[tid] = 0;
            cnt2[tid] = 0;
        } else {
            qpk[tid] = make_uint4(0u, 0u, 0u, 0u);
        }
    }
    __syncthreads();

    // B fragment: lane l<16 holds B[k=0..7][col=l] = [-2f_col(0..6), 1]
    U4H8 ub; ub.u = (lane < 16) ? qpk[lane] : make_uint4(0u, 0u, 0u, 0u);
    const f16x8 bfrag = ub.h;
    const f32x4 z4 = {0.f, 0.f, 0.f, 0.f};
    const int tilebase = wave * 64;           // 64 tiles/wave, j = t*16+row

    // ---- pass 1: MFMA screen, keep 4 per-r slot-mins per lane ----
    float lm0 = INFINITY, lm1 = INFINITY, lm2 = INFINITY, lm3 = INFINITY;
#pragma unroll 4
    for (int tt = 0; tt < 64; ++tt) {
        int t = tilebase + tt;
        uint4 au = make_uint4(0u, 0u, 0u, 0u);
        if (lane < 16) au = fh[t * 16 + lane];     // A[row=lane][k=0..7]
        U4H8 ua; ua.u = au;
        f32x4 acc = __builtin_amdgcn_mfma_f32_16x16x32_f16(ua.h, bfrag, z4, 0, 0, 0);
        lm0 = fminf(lm0, acc[0]);
        lm1 = fminf(lm1, acc[1]);
        lm2 = fminf(lm2, acc[2]);
        lm3 = fminf(lm3, acc[3]);
    }
    {   // slot = wave*16 + lg*4 + r; each slot covers 64 distinct j's
        int sb = wave * 16 + lg * 4;
        Lmin[(sb + 0) * 16 + col] = lm0;
        Lmin[(sb + 1) * 16 + col] = lm1;
        Lmin[(sb + 2) * 16 + col] = lm2;
        Lmin[(sb + 3) * 16 + col] = lm3;
    }
    __syncthreads();

    // ---- EXACT 34th-smallest of 128 slot-mins (wave w -> query w) ----
    // >=34 slots <= T -> >=34 distinct j (>=33 non-diag) with screen <= T.
    {
        const int q = wave;
        unsigned ov0 = ordu(Lmin[lane * 16 + q]);
        unsigned ov1 = ordu(Lmin[(64 + lane) * 16 + q]);
        unsigned lo = 0u, hi = 0xFFFFFFFFu;
        while (lo < hi) {
            unsigned mid = lo + ((hi - lo) >> 1);
            int cnt = __popcll(__ballot(ov0 <= mid))
                    + __popcll(__ballot(ov1 <= mid));
            if (cnt >= 34) hi = mid; else lo = mid + 1;
        }
        if (lane == 0) selT[q] = lo;
    }
    __syncthreads();

    // thresholds: exact-32nd <= T+DELTA; screen of top-32 member <= T+2*DELTA.
    // Clamp-to-zero ties covered via -sqi terms.
    if (tid < 16) {
        if (tid < QB) {
            float Ts = unordu(selT[tid]);
            float sq_ = sqfL[tid];
            exqL[tid] = fmaxf(Ts + DELTA, -sq_);
            scrL[tid] = fmaxf(Ts + 2.f * DELTA, -sq_ + DELTA);
        } else {
            scrL[tid] = -INFINITY;            // padding queries never survive
        }
    }
    __syncthreads();

    // ---- pass 2: MFMA re-screen, extract survivor j's ----
    {
        float myscr = scrL[col];
#pragma unroll 4
        for (int tt = 0; tt < 64; ++tt) {
            int t = tilebase + tt;
            uint4 au = make_uint4(0u, 0u, 0u, 0u);
            if (lane < 16) au = fh[t * 16 + lane];
            U4H8 ua; ua.u = au;
            f32x4 acc = __builtin_amdgcn_mfma_f32_16x16x32_f16(ua.h, bfrag, z4, 0, 0, 0);
#pragma unroll
            for (int r = 0; r < 4; ++r) {
                if (acc[r] <= myscr) {
                    int j = t * 16 + lg * 4 + r;
                    int p = atomicAdd(&scnt[col], 1);
                    if (p < SCAP) ent[col][p] = (unsigned short)j;
                }
            }
        }
    }
    __syncthreads();   // Lmin reads done; cand may be overwritten now

    // ---- exact fp32 phase over survivors, prune at exqL -> rank keys ----
#pragma unroll
    for (int q = 0; q < QB; ++q) {
        int n = scnt[q];
        if (n > SCAP) n = SCAP;
        float thr = exqL[q];
        for (int t = tid; t < n; t += NT) {
            int j = ent[q][t];
            float4 b0 = xs4[j * 2];
            float4 b1 = xs4[j * 2 + 1];       // .w = sq_j
            float m = dist_m(b0, b1, b1.w, qA[q], qBv[q]);
            if (m <= thr && j != i0 + q) {
                float d2c = fmaxf(sqi[q] + m, 0.f);
                u64 key = ((u64)__float_as_uint(d2c) << 32) | (unsigned)j;
                int p = atomicAdd(&cnt2[q], 1);
                if (p < ECAP2) cand[q][p] = key;
            }
        }
    }
    __syncthreads();

    // ---- selection: wave w -> query w, exact rank-by-counting ----
    {
        const int q = wave;
        const int M = cnt2[q];
        if (scnt[q] <= SCAP && M >= K && M <= ECAP2) {
            for (int p = lane; p < M; p += 64) {
                u64 my = cand[q][p];
                int rank = 0;
                for (int m = 0; m < M; ++m)
                    rank += (cand[q][m] < my) ? 1 : 0;
                if (rank < K) nbr[q][rank] = (int)(my & 0xffffffffu);
            }
        }
    }
    __syncthreads();

    // ---- exact fallback (cold, ~never) ----
#pragma unroll 1
    for (int q = 0; q < QB; ++q) {
        int s = scnt[q];                      // block-uniform
        int M = cnt2[q];
        if (s > SCAP || M < K || M > ECAP2) {
            const int iq = i0 + q;
            const float* xq = x + iq * 8;
            float4 A  = *reinterpret_cast<const float4*>(xq);
            float4 Bv = *reinterpret_cast<const float4*>(xq + 4);
            Bv.w = xs4[iq * 2 + 1].w;
            float lastv = -1.0f; int lasti = -1;
#pragma unroll 1
            for (int it = 0; it < K; ++it) {
                float best = INFINITY; int bidx = 0x7fffffff;
#pragma unroll 1
                for (int c = 0; c < CPT; ++c) {
                    int j = c * NT + tid;
                    float4 b0 = xs4[j * 2];
                    float4 b1 = xs4[j * 2 + 1];
                    float m = dist_m(b0, b1, b1.w, A, Bv);
                    float d2c = fmaxf(Bv.w + m, 0.f);
                    if (j == iq) continue;
                    bool gt = (d2c > lastv) || (d2c == lastv && j > lasti);
                    if (gt && (d2c < best || (d2c == best && j < bidx))) {
                        best = d2c; bidx = j;
                    }
                }
#pragma unroll
                for (int off = 32; off > 0; off >>= 1) {
                    float ov = __shfl_down(best, off);
                    int   oi = __shfl_down(bidx, off);
                    if (ov < best || (ov == best && oi < bidx)) { best = ov; bidx = oi; }
                }
                if (lane == 0) { redv[wave] = best; redi[wave] = bidx; }
                __syncthreads();
                if (tid == 0) {
                    float bv = redv[0]; int bi = redi[0];
#pragma unroll
                    for (int w = 1; w < 8; ++w)
                        if (redv[w] < bv || (redv[w] == bv && redi[w] < bi)) {
                            bv = redv[w]; bi = redi[w];
                        }
                    bcv = bv; bci = bi;
                    nbr[q][it] = bi;
                }
                __syncthreads();
                lastv = bcv; lasti = bci;
            }
        }
    }
    __syncthreads();

    // ---- attention epilogue: wave w -> query w, lanes 0..31 ----
    {
        const int q  = wave;
        const int iq = i0 + q;
        if (lane < K) {
            int nk = nbr[q][lane];
            float s = 0.f;
#pragma unroll
            for (int c = 0; c < D; ++c) s += outb[iq * D + c] * aw[c];
            float xp[D + 1];
#pragma unroll
            for (int c = 0; c < D; ++c) {
                float on = outb[nk * D + c];
                xp[c] = on;
                s += on * aw[D + c];
            }
            xp[D] = x[nk * 8 + 7];

            float m = s;
#pragma unroll
            for (int off = 16; off > 0; off >>= 1) m = fmaxf(m, __shfl_xor(m, off, 32));
            float e = expf(s - m);
            float sum = e;
#pragma unroll
            for (int off = 16; off > 0; off >>= 1) sum += __shfl_xor(sum, off, 32);
            float att = e / sum;

            float agg[D + 1];
#pragma unroll
            for (int dd = 0; dd < D + 1; ++dd) {
                float v = att * xp[dd];
#pragma unroll
                for (int off = 16; off > 0; off >>= 1) v += __shfl_xor(v, off, 32);
                agg[dd] = v;
            }

            if (lane < D) {
                float o = outb[iq * D + lane];
                dout[iq * 15 + lane] = o;
                dout[N_NODES * 15 + iq * 15 + lane] = o;
            }
            if (lane < D + 1) {
                float av_ = agg[0];
#pragma unroll
                for (int dd = 1; dd < D + 1; ++dd) av_ = (lane == dd) ? agg[dd] : av_;
                dout[iq * 15 + D + lane] = av_;
                dout[N_NODES * 15 + iq * 15 + D + lane] = av_;
            }
            if (iq == N_NODES - 1) dout[2 * N_NODES * 15 + lane] = att;
        }
    }
}

extern "C" void kernel_launch(void* const* d_in, const int* in_sizes, int n_in,
                              void* d_out, int out_size, void* d_ws, size_t ws_size,
                              hipStream_t stream) {
    (void)in_sizes; (void)n_in; (void)out_size; (void)ws_size;
    const float* x = (const float*)d_in[0];
    const float* W = (const float*)d_in[1];
    const float* a = (const float*)d_in[2];
    float* out   = (float*)d_out;
    float* outb  = (float*)d_ws;                      // 8192*7 f32 (224 KB)
    uint4* fh    = (uint4*)(outb + N_NODES * D);      // 8192*16 B (128 KB)
    float4* xsq4 = (float4*)(fh + N_NODES);           // 8192*32 B (256 KB)

    hipLaunchKernelGGL(precompute_kernel, dim3(N_NODES / 256), dim3(256),
                       0, stream, x, W, outb, fh, xsq4);
    hipLaunchKernelGGL(gat_kernel, dim3(N_NODES / QB), dim3(NT),
                       0, stream, x, a, outb, fh, xsq4, out);
}

// Round 12
// 73.641 us; speedup vs baseline: 1.2228x; 1.2228x over previous
//
#include <hip/hip_runtime.h>
#include <math.h>
#include <stdint.h>

#define N_NODES 8192
#define D 7
#define K 32
#define NT 512
#define QB 16                // queries per block == MFMA columns (all real)
#define CPT (N_NODES / NT)
#define TPW 64               // tiles per wave, full pass (8192 / 16 rows / 8 waves)
#define SCAP 320             // screen-survivor capacity per query
#define ECAP2 256            // exact-pruned rank capacity per query
#define DELTA 0.125f         // f16 screen error bound (analytic <= ~0.09)

typedef unsigned long long u64;
typedef _Float16 h2 __attribute__((ext_vector_type(2)));
typedef _Float16 f16x8 __attribute__((ext_vector_type(8)));
typedef float f32x4 __attribute__((ext_vector_type(4)));
union U4H8 { uint4 u; f16x8 h; };

__device__ __forceinline__ unsigned pkh(float a, float b) {
    union { h2 h; unsigned u; } t;
    t.h[0] = (_Float16)a; t.h[1] = (_Float16)b; return t.u;
}
// order-preserving float<->uint (total order)
__device__ __forceinline__ unsigned ordu(float f) {
    unsigned u = __float_as_uint(f);
    return (u & 0x80000000u) ? ~u : (u | 0x80000000u);
}
__device__ __forceinline__ float unordu(unsigned o) {
    unsigned u = (o & 0x80000000u) ? (o & 0x7fffffffu) : ~o;
    return __uint_as_float(u);
}

// exact m = sqj - 2*dot(fi, fj); identical rounding chain everywhere.
__device__ __forceinline__ float dist_m(float4 b0, float4 b1, float sqj,
                                        float4 A, float4 B) {
    float dot = A.x * b0.x;
    dot = fmaf(A.y, b0.y, dot);
    dot = fmaf(A.z, b0.z, dot);
    dot = fmaf(A.w, b0.w, dot);
    dot = fmaf(B.x, b1.x, dot);
    dot = fmaf(B.y, b1.y, dot);
    dot = fmaf(B.z, b1.z, dot);
    return fmaf(-2.0f, dot, sqj);
}

// ---------------------------------------------------------------------------
// Kernel 1: outb = clip(feat @ W^T), fh = f16 [f0..f6,sq] (16 B/node),
//           xsq = f32 [f0..f6, sq] (32 B/node).
// ---------------------------------------------------------------------------
__global__ __launch_bounds__(256)
void precompute_kernel(const float* __restrict__ x, const float* __restrict__ W,
                       float* __restrict__ outb, uint4* __restrict__ fh,
                       float4* __restrict__ xsq4)
{
    int n = blockIdx.x * 256 + threadIdx.x;
    float4 v0 = *reinterpret_cast<const float4*>(x + n * 8);
    float4 v1 = *reinterpret_cast<const float4*>(x + n * 8 + 4);
    float f[D] = {v0.x, v0.y, v0.z, v0.w, v1.x, v1.y, v1.z};
    float sq = 0.f;
#pragma unroll
    for (int c = 0; c < D; ++c) sq += f[c] * f[c];
    uint4 h;
    h.x = pkh(f[0], f[1]); h.y = pkh(f[2], f[3]);
    h.z = pkh(f[4], f[5]); h.w = pkh(f[6], sq);
    fh[n] = h;
    xsq4[n * 2]     = v0;
    xsq4[n * 2 + 1] = make_float4(v1.x, v1.y, v1.z, sq);
#pragma unroll
    for (int r = 0; r < D; ++r) {
        float acc = 0.f;
#pragma unroll
        for (int c = 0; c < D; ++c) acc += f[c] * W[r * D + c];
        acc = fminf(fmaxf(acc, -1.f), 1.f);
        outb[n * D + r] = acc;
    }
}

// ---------------------------------------------------------------------------
// Kernel 2: exact top-32 (jax.lax.top_k order) + attention. QB=16 (all MFMA
// cols real). Half-sample MFMA screen -> 34th-of-128 slot-min threshold ->
// full MFMA extraction at T+2*DELTA -> exact fp32 prune at T+DELTA -> rank.
// ---------------------------------------------------------------------------
__global__ __launch_bounds__(NT, 2)
void gat_kernel(const float* __restrict__ x, const float* __restrict__ aw,
                const float* __restrict__ outb, const uint4* __restrict__ fh,
                const float4* __restrict__ xs4, float* __restrict__ dout)
{
    __shared__ u64      cand[QB][ECAP2];      // 32 KB (aliases Lmin[128][16])
    __shared__ unsigned short ent[QB][SCAP];  // 10 KB
    __shared__ int      nbr[QB][K];           // 2 KB
    __shared__ uint4    qpk[QB];              // B-operand f16 rows
    __shared__ float4   qf4[QB][2];           // f32 query feats; [1].w = sqi
    __shared__ float    sqfL[QB];
    __shared__ unsigned selT[QB];
    __shared__ float    exqL[QB];             // exact prune threshold
    __shared__ float    scrL[QB];             // screen threshold
    __shared__ int      scnt[QB];
    __shared__ int      cnt2[QB];
    __shared__ float    redv[8];
    __shared__ int      redi[8];
    __shared__ float    bcv;
    __shared__ int      bci;

    float* Lmin = (float*)cand;               // [128 slots][16 cols] f32, 8 KB

    const int tid  = threadIdx.x;
    const int lane = tid & 63;
    const int wave = tid >> 6;
    const int i0   = blockIdx.x * QB;
    const int col  = lane & 15;
    const int lg   = lane >> 4;

    if (tid < QB) {
        float4 b0 = xs4[(i0 + tid) * 2];
        float4 b1 = xs4[(i0 + tid) * 2 + 1];  // .w = sq_i
        qpk[tid] = make_uint4(pkh(-2.f * b0.x, -2.f * b0.y),
                              pkh(-2.f * b0.z, -2.f * b0.w),
                              pkh(-2.f * b1.x, -2.f * b1.y),
                              pkh(-2.f * b1.z, 1.0f));
        qf4[tid][0] = b0;
        qf4[tid][1] = b1;
        sqfL[tid]   = b1.w;
        scnt[tid] = 0;
        cnt2[tid] = 0;
    }
    __syncthreads();

    // B fragment: lane l<16 holds B[k=0..7][col=l] = [-2f_col(0..6), 1]
    U4H8 ub; ub.u = (lane < QB) ? qpk[lane] : make_uint4(0u, 0u, 0u, 0u);
    const f16x8 bfrag = ub.h;
    const f32x4 z4 = {0.f, 0.f, 0.f, 0.f};
    const int tb = wave * TPW;                // wave's 64-tile stripe

    // ---- pass 1: HALF-SAMPLE MFMA screen (32 tiles), 4 slot-mins/lane ----
    float lm0 = INFINITY, lm1 = INFINITY, lm2 = INFINITY, lm3 = INFINITY;
#pragma unroll 4
    for (int tt = 0; tt < TPW / 2; ++tt) {
        int t = tb + tt;
        uint4 au = make_uint4(0u, 0u, 0u, 0u);
        if (lane < 16) au = fh[t * 16 + lane];     // A[row=lane][k=0..7]
        U4H8 ua; ua.u = au;
        f32x4 acc = __builtin_amdgcn_mfma_f32_16x16x32_f16(ua.h, bfrag, z4, 0, 0, 0);
        lm0 = fminf(lm0, acc[0]);
        lm1 = fminf(lm1, acc[1]);
        lm2 = fminf(lm2, acc[2]);
        lm3 = fminf(lm3, acc[3]);
    }
    {   // slot = wave*16 + lg*4 + r; slots cover pairwise-distinct j's
        int sb = wave * 16 + lg * 4;
        Lmin[(sb + 0) * 16 + col] = lm0;
        Lmin[(sb + 1) * 16 + col] = lm1;
        Lmin[(sb + 2) * 16 + col] = lm2;
        Lmin[(sb + 3) * 16 + col] = lm3;
    }
    __syncthreads();

    // ---- EXACT 34th-smallest of 128 slot-mins; wave w -> queries w, w+8 ----
    // >=34 slots <= T -> >=34 distinct j (>=33 non-diag) with screen <= T
    // -> exact 32nd <= T+DELTA; top-32 member's screen <= T+2*DELTA.
#pragma unroll
    for (int h = 0; h < 2; ++h) {
        const int q = wave + h * 8;
        unsigned ov0 = ordu(Lmin[lane * 16 + q]);
        unsigned ov1 = ordu(Lmin[(64 + lane) * 16 + q]);
        unsigned lo = 0u, hi = 0xFFFFFFFFu;
        while (lo < hi) {
            unsigned mid = lo + ((hi - lo) >> 1);
            int cnt = __popcll(__ballot(ov0 <= mid))
                    + __popcll(__ballot(ov1 <= mid));
            if (cnt >= 34) hi = mid; else lo = mid + 1;
        }
        if (lane == 0) selT[q] = lo;
    }
    __syncthreads();

    if (tid < QB) {
        float Ts  = unordu(selT[tid]);
        float sq_ = sqfL[tid];
        exqL[tid] = fmaxf(Ts + DELTA, -sq_);             // exact keep
        scrL[tid] = fmaxf(Ts + 2.f * DELTA, -sq_ + DELTA); // screen keep
    }
    __syncthreads();

    // ---- pass 2: FULL MFMA extraction with min4 fast-path ----
    {
        float myscr = scrL[col];
#pragma unroll 4
        for (int tt = 0; tt < TPW; ++tt) {
            int t = tb + tt;
            uint4 au = make_uint4(0u, 0u, 0u, 0u);
            if (lane < 16) au = fh[t * 16 + lane];
            U4H8 ua; ua.u = au;
            f32x4 acc = __builtin_amdgcn_mfma_f32_16x16x32_f16(ua.h, bfrag, z4, 0, 0, 0);
            float v01 = fminf(acc[0], acc[1]);
            float v23 = fminf(acc[2], acc[3]);
            if (fminf(v01, v23) <= myscr) {
#pragma unroll
                for (int r = 0; r < 4; ++r) {
                    if (acc[r] <= myscr) {
                        int j = t * 16 + lg * 4 + r;
                        int p = atomicAdd(&scnt[col], 1);
                        if (p < SCAP) ent[col][p] = (unsigned short)j;
                    }
                }
            }
        }
    }
    __syncthreads();   // Lmin dead; cand may be overwritten now

    // ---- exact fp32 phase over survivors, prune at exqL -> rank keys ----
#pragma unroll 1
    for (int q = 0; q < QB; ++q) {
        int n = scnt[q];
        if (n > SCAP) n = SCAP;
        float4 A  = qf4[q][0];
        float4 Bv = qf4[q][1];                // .w = sqi
        float thr = exqL[q];
        for (int t = tid; t < n; t += NT) {
            int j = ent[q][t];
            float4 b0 = xs4[j * 2];
            float4 b1 = xs4[j * 2 + 1];       // .w = sq_j
            float m = dist_m(b0, b1, b1.w, A, Bv);
            if (m <= thr && j != i0 + q) {
                float d2c = fmaxf(Bv.w + m, 0.f);
                u64 key = ((u64)__float_as_uint(d2c) << 32) | (unsigned)j;
                int p = atomicAdd(&cnt2[q], 1);
                if (p < ECAP2) cand[q][p] = key;
            }
        }
    }
    __syncthreads();

    // ---- selection: wave w -> queries w, w+8; exact rank-by-counting ----
#pragma unroll
    for (int h = 0; h < 2; ++h) {
        const int q = wave + h * 8;
        const int M = cnt2[q];
        if (scnt[q] <= SCAP && M >= K && M <= ECAP2) {
            for (int p = lane; p < M; p += 64) {
                u64 my = cand[q][p];
                int rank = 0;
                for (int m = 0; m < M; ++m)
                    rank += (cand[q][m] < my) ? 1 : 0;
                if (rank < K) nbr[q][rank] = (int)(my & 0xffffffffu);
            }
        }
    }
    __syncthreads();

    // ---- exact fallback (cold, ~never) ----
#pragma unroll 1
    for (int q = 0; q < QB; ++q) {
        int s = scnt[q];                      // block-uniform
        int M = cnt2[q];
        if (s > SCAP || M < K || M > ECAP2) {
            const int iq = i0 + q;
            float4 A  = qf4[q][0];
            float4 Bv = qf4[q][1];
            float lastv = -1.0f; int lasti = -1;
#pragma unroll 1
            for (int it = 0; it < K; ++it) {
                float best = INFINITY; int bidx = 0x7fffffff;
#pragma unroll 1
                for (int c = 0; c < CPT; ++c) {
                    int j = c * NT + tid;
                    float4 b0 = xs4[j * 2];
                    float4 b1 = xs4[j * 2 + 1];
                    float m = dist_m(b0, b1, b1.w, A, Bv);
                    float d2c = fmaxf(Bv.w + m, 0.f);
                    if (j == iq) continue;
                    bool gt = (d2c > lastv) || (d2c == lastv && j > lasti);
                    if (gt && (d2c < best || (d2c == best && j < bidx))) {
                        best = d2c; bidx = j;
                    }
                }
#pragma unroll
                for (int off = 32; off > 0; off >>= 1) {
                    float ov = __shfl_down(best, off);
                    int   oi = __shfl_down(bidx, off);
                    if (ov < best || (ov == best && oi < bidx)) { best = ov; bidx = oi; }
                }
                if (lane == 0) { redv[wave] = best; redi[wave] = bidx; }
                __syncthreads();
                if (tid == 0) {
                    float bv = redv[0]; int bi = redi[0];
#pragma unroll
                    for (int w = 1; w < 8; ++w)
                        if (redv[w] < bv || (redv[w] == bv && redi[w] < bi)) {
                            bv = redv[w]; bi = redi[w];
                        }
                    bcv = bv; bci = bi;
                    nbr[q][it] = bi;
                }
                __syncthreads();
                lastv = bcv; lasti = bci;
            }
        }
    }
    __syncthreads();

    // ---- attention epilogue: wave w -> queries w, w+8; lanes 0..31 ----
#pragma unroll 1
    for (int h = 0; h < 2; ++h) {
        const int q  = wave + h * 8;
        const int iq = i0 + q;
        if (lane < K) {
            int nk = nbr[q][lane];
            float s = 0.f;
#pragma unroll
            for (int c = 0; c < D; ++c) s += outb[iq * D + c] * aw[c];
            float xp[D + 1];
#pragma unroll
            for (int c = 0; c < D; ++c) {
                float on = outb[nk * D + c];
                xp[c] = on;
                s += on * aw[D + c];
            }
            xp[D] = x[nk * 8 + 7];

            float m = s;
#pragma unroll
            for (int off = 16; off > 0; off >>= 1) m = fmaxf(m, __shfl_xor(m, off, 32));
            float e = expf(s - m);
            float sum = e;
#pragma unroll
            for (int off = 16; off > 0; off >>= 1) sum += __shfl_xor(sum, off, 32);
            float att = e / sum;

            float agg[D + 1];
#pragma unroll
            for (int dd = 0; dd < D + 1; ++dd) {
                float v = att * xp[dd];
#pragma unroll
                for (int off = 16; off > 0; off >>= 1) v += __shfl_xor(v, off, 32);
                agg[dd] = v;
            }

            if (lane < D) {
                float o = outb[iq * D + lane];
                dout[iq * 15 + lane] = o;
                dout[N_NODES * 15 + iq * 15 + lane] = o;
            }
            if (lane < D + 1) {
                float av_ = agg[0];
#pragma unroll
                for (int dd = 1; dd < D + 1; ++dd) av_ = (lane == dd) ? agg[dd] : av_;
                dout[iq * 15 + D + lane] = av_;
                dout[N_NODES * 15 + iq * 15 + D + lane] = av_;
            }
            if (iq == N_NODES - 1) dout[2 * N_NODES * 15 + lane] = att;
        }
    }
}

extern "C" void kernel_launch(void* const* d_in, const int* in_sizes, int n_in,
                              void* d_out, int out_size, void* d_ws, size_t ws_size,
                              hipStream_t stream) {
    (void)in_sizes; (void)n_in; (void)out_size; (void)ws_size;
    const float* x = (const float*)d_in[0];
    const float* W = (const float*)d_in[1];
    const float* a = (const float*)d_in[2];
    float* out   = (float*)d_out;
    float* outb  = (float*)d_ws;                      // 8192*7 f32 (224 KB)
    uint4* fh    = (uint4*)(outb + N_NODES * D);      // 8192*16 B (128 KB)
    float4* xsq4 = (float4*)(fh + N_NODES);           // 8192*32 B (256 KB)

    hipLaunchKernelGGL(precompute_kernel, dim3(N_NODES / 256), dim3(256),
                       0, stream, x, W, outb, fh, xsq4);
    hipLaunchKernelGGL(gat_kernel, dim3(N_NODES / QB), dim3(NT),
                       0, stream, x, a, outb, fh, xsq4, out);
}